// Round 6
// baseline (218.924 us; speedup 1.0000x reference)
//
#include <hip/hip_runtime.h>
#include <math.h>

#define FMPX 40
#define NPOS 1600          // 40*40
#define NCLS 80
#define NBOX 8000
#define KDIM 512
#define CAP  256           // per-class candidate capacity (mean ~100/class, +15 sigma)

// anchor (w,h) pairs
__constant__ float c_aw[5] = {17.f, 55.f, 92.f, 202.f, 289.f};
__constant__ float c_ah[5] = {25.f, 75.f, 206.f, 21.f, 311.f};

__device__ __forceinline__ float sigf(float x) { return 1.0f / (1.0f + expf(-x)); }

// ---------------------------------------------------------------------------
// K1: the three 1x1-conv GEMMs — NO LDS, NO barriers.
// R3: A+W in LDS -> LDS-pipe-bound (50us). R4: W s_load + A ds_read -> lgkm
// mixing serialized both pipes (77us). R5: W ds_read_b128 broadcast + A
// global -> LDS unit still the per-CU bottleneck (43us, 8 b128/step shared
// by 10.5 waves). R6: A from global (vmcnt, register double-buffer) and W
// from the SCALAR pipe (og readfirstlane'd -> provably uniform -> s_load).
// lgkmcnt now tracks ONLY SMEM, so the per-step lgkmcnt(0) stalls overlap
// across waves while A pipelining survives — R4's failure mode is gone.
// grid = (25 M-tiles of 64 pos, 27 N-tiles of 16 outs):
//   nTile 0..24: cls outs (cls_feat); 25/26: the 25 obj+reg outs (reg_feat).
// Per-acc FMA order strictly sequential ascending k, operand form a*w —
// bitwise-identical to R1-R5 (absmax stable at 2.0 across all rounds).
// ---------------------------------------------------------------------------
__global__ __launch_bounds__(256) void k_gemm(
    const float* __restrict__ cls_feat, const float* __restrict__ reg_feat,
    const float* __restrict__ w_obj, const float* __restrict__ b_obj,
    const float* __restrict__ w_cls, const float* __restrict__ b_cls,
    const float* __restrict__ w_reg, const float* __restrict__ b_reg,
    float* __restrict__ clsRaw,   // [1600][400]
    float* __restrict__ roRaw)    // [1600][25]: 0..4 obj, 5..24 reg
{
    const int mTile = blockIdx.x;          // 0..24
    const int nTile = blockIdx.y;          // 0..26
    const int hw0   = mTile * 64;
    const bool isCls = (nTile < 25);
    const float* feat = isCls ? cls_feat : reg_feat;

    const int pos = threadIdx.x & 63;
    // force provable wave-uniformity so W loads scalarize to s_load
    const int og = __builtin_amdgcn_readfirstlane(threadIdx.x >> 6);   // 0..3

    const float* wrow[4];
    float bias[4];
    bool ok[4];
#pragma unroll
    for (int j = 0; j < 4; j++) {
        if (isCls) {
            int o = nTile * 16 + og * 4 + j;
            wrow[j] = w_cls + o * KDIM; bias[j] = b_cls[o]; ok[j] = true;
        } else {
            int o = (nTile - 25) * 16 + og * 4 + j;   // 0..31
            if (o < 5)       { wrow[j] = w_obj + o * KDIM;       bias[j] = b_obj[o];     ok[j] = true; }
            else if (o < 25) { wrow[j] = w_reg + (o - 5) * KDIM; bias[j] = b_reg[o - 5]; ok[j] = true; }
            else             { wrow[j] = w_obj;                  bias[j] = 0.0f;         ok[j] = false; }
        }
    }

    // A pointer for this lane's position; k strides by NPOS floats.
    const float* ap = feat + hw0 + pos;

    // Initial A prefetch (k = 0..15), register double buffer.
    float A0[8], A1[8];
#pragma unroll
    for (int t = 0; t < 8; t++) A0[t] = ap[t * NPOS];
#pragma unroll
    for (int t = 0; t < 8; t++) A1[t] = ap[(8 + t) * NPOS];

    float acc[4] = {0.f, 0.f, 0.f, 0.f};

    for (int kk = 0; kk < KDIM - 16; kk += 16) {
        // consume A0 (k = kk..kk+7); W via uniform scalar reads
#pragma unroll
        for (int j = 0; j < 4; j++) {
            const float* wp = wrow[j] + kk;
            acc[j] += A0[0] * wp[0]; acc[j] += A0[1] * wp[1];
            acc[j] += A0[2] * wp[2]; acc[j] += A0[3] * wp[3];
            acc[j] += A0[4] * wp[4]; acc[j] += A0[5] * wp[5];
            acc[j] += A0[6] * wp[6]; acc[j] += A0[7] * wp[7];
        }
#pragma unroll
        for (int t = 0; t < 8; t++) A0[t] = ap[(kk + 16 + t) * NPOS];
        // consume A1 (k = kk+8..kk+15)
#pragma unroll
        for (int j = 0; j < 4; j++) {
            const float* wp = wrow[j] + kk + 8;
            acc[j] += A1[0] * wp[0]; acc[j] += A1[1] * wp[1];
            acc[j] += A1[2] * wp[2]; acc[j] += A1[3] * wp[3];
            acc[j] += A1[4] * wp[4]; acc[j] += A1[5] * wp[5];
            acc[j] += A1[6] * wp[6]; acc[j] += A1[7] * wp[7];
        }
#pragma unroll
        for (int t = 0; t < 8; t++) A1[t] = ap[(kk + 24 + t) * NPOS];
    }
    // tail: k = 496..511
    {
        const int kk = KDIM - 16;
#pragma unroll
        for (int j = 0; j < 4; j++) {
            const float* wp = wrow[j] + kk;
            acc[j] += A0[0] * wp[0]; acc[j] += A0[1] * wp[1];
            acc[j] += A0[2] * wp[2]; acc[j] += A0[3] * wp[3];
            acc[j] += A0[4] * wp[4]; acc[j] += A0[5] * wp[5];
            acc[j] += A0[6] * wp[6]; acc[j] += A0[7] * wp[7];
        }
#pragma unroll
        for (int j = 0; j < 4; j++) {
            const float* wp = wrow[j] + kk + 8;
            acc[j] += A1[0] * wp[0]; acc[j] += A1[1] * wp[1];
            acc[j] += A1[2] * wp[2]; acc[j] += A1[3] * wp[3];
            acc[j] += A1[4] * wp[4]; acc[j] += A1[5] * wp[5];
            acc[j] += A1[6] * wp[6]; acc[j] += A1[7] * wp[7];
        }
    }

    const int hw = hw0 + pos;
    if (isCls) {
        float4 rv = make_float4(acc[0] + bias[0], acc[1] + bias[1],
                                acc[2] + bias[2], acc[3] + bias[3]);
        *(float4*)&clsRaw[hw * 400 + nTile * 16 + og * 4] = rv;
    } else {
#pragma unroll
        for (int j = 0; j < 4; j++) {
            int o = (nTile - 25) * 16 + og * 4 + j;
            if (ok[j]) roRaw[hw * 25 + o] = acc[j] + bias[j];
        }
    }
}

// ---------------------------------------------------------------------------
// K2: per-box scores, argmax label, decode, outputs. float4 class loads:
// lanes 0..19 cover 4 classes each (in-lane first-max, cross-lane lowest-
// index tiebreak == jnp.argmax first-max semantics).
// 2000 blocks x 256 thr; each of the 4 waves handles one box.
// ---------------------------------------------------------------------------
__global__ __launch_bounds__(256) void k_box(
    const float* __restrict__ clsRaw, const float* __restrict__ roRaw,
    float* __restrict__ out,          // d_out: [32000 bboxes][8000 score][8000 labels][8000 keep]
    float4* __restrict__ nmsBox, float* __restrict__ nmsArea,
    float2* __restrict__ sl)          // packed (score,label) for k_nms scan
{
    const int n = blockIdx.x * 4 + (threadIdx.x >> 6);   // box index 0..7999
    const int lane = threadIdx.x & 63;
    const int hw = n / 5, a = n % 5;

    const float sobj = sigf(roRaw[hw * 25 + a]);
    const float* cbase = clsRaw + hw * 400 + a * 80;

    const int l4 = (lane < 20) ? lane : 19;     // clamp for safe address
    float4 cs = *(const float4*)(cbase + l4 * 4);

    // in-lane first-max over classes l4*4 .. l4*4+3 (strict > keeps first)
    float s0 = sqrtf(sobj * sigf(cs.x));
    float s1 = sqrtf(sobj * sigf(cs.y));
    float s2 = sqrtf(sobj * sigf(cs.z));
    float s3 = sqrtf(sobj * sigf(cs.w));
    float v = s0; int bi = l4 * 4;
    if (s1 > v) { v = s1; bi = l4 * 4 + 1; }
    if (s2 > v) { v = s2; bi = l4 * 4 + 2; }
    if (s3 > v) { v = s3; bi = l4 * 4 + 3; }
    if (lane >= 20) { v = -1.0f; bi = 0x7FFFFFFF; }  // scores are always > 0

    // cross-lane: max score, ties -> lowest class
#pragma unroll
    for (int off = 32; off >= 1; off >>= 1) {
        float ov = __shfl_xor(v, off);
        int   oi = __shfl_xor(bi, off);
        if (ov > v || (ov == v && oi < bi)) { v = ov; bi = oi; }
    }

    if (lane == 0) {
        const float* rp = roRaw + hw * 25 + 5 + a * 4;
        float r0 = rp[0], r1 = rp[1], r2 = rp[2], r3 = rp[3];
        float gx = (float)(hw % FMPX), gy = (float)(hw / FMPX);
        float cx = (sigf(r0) + gx) * 32.0f;
        float cy = (sigf(r1) + gy) * 32.0f;
        float wv = expf(r2) * c_aw[a];
        float hv = expf(r3) * c_ah[a];
        float x1 = cx - wv * 0.5f, y1 = cy - hv * 0.5f;
        float x2 = cx + wv * 0.5f, y2 = cy + hv * 0.5f;

        out[n * 4 + 0] = x1; out[n * 4 + 1] = y1;
        out[n * 4 + 2] = x2; out[n * 4 + 3] = y2;
        out[32000 + n] = v;
        out[40000 + n] = (float)bi;
        out[48000 + n] = 0.0f;            // keep init (k_nms sets 1s later)
        sl[n] = make_float2(v, (float)bi);

        // b2: reinterpret x1y1x2y2 as cxcywh (faithful to the reference nms())
        float nx1 = x1 - x2 * 0.5f, ny1 = y1 - y2 * 0.5f;
        float nx2 = x1 + x2 * 0.5f, ny2 = y1 + y2 * 0.5f;
        nmsBox[n]  = make_float4(nx1, ny1, nx2, ny2);
        nmsArea[n] = (nx2 - nx1) * (ny2 - ny1);
    }
}

// ---------------------------------------------------------------------------
// K3: per-class greedy NMS — ONE WAVE per class, register-resident greedy.
// R5 lesson: 41us from ~140 sequential greedy iterations each paying a
// 4-wave __syncthreads + LDS supp latency. Now: candidates in REGISTERS
// (4 slots/lane, CAP=256), supp = 4-bit register mask/lane, pivot box and
// supp bit broadcast via v_cndmask + __shfl. LDS only for the bitonic sort
// (deterministic (score desc, idx asc) == stable argsort(-score) per class).
// Zero barriers and zero LDS traffic in the m-loop.
// ---------------------------------------------------------------------------
__global__ __launch_bounds__(64) void k_nms(
    const float2* __restrict__ sl,
    const float4* __restrict__ nmsBox, const float* __restrict__ nmsArea,
    float* __restrict__ keepOut)
{
    const int c = blockIdx.x;
    const int lane = threadIdx.x;

    __shared__ float ss[CAP];
    __shared__ int   si[CAP];
    __shared__ int   cnt;

    if (lane == 0) cnt = 0;
    __syncthreads();

    // scan all boxes, 2 per float4 load, compact matches into LDS
    const float4* sl4 = (const float4*)sl;
    for (int q = lane; q < NBOX / 2; q += 64) {
        float4 p = sl4[q];
        if (p.x >= 0.3f && (int)p.y == c) {
            int t = atomicAdd(&cnt, 1);
            if (t < CAP) { ss[t] = p.x; si[t] = 2 * q; }
        }
        if (p.z >= 0.3f && (int)p.w == c) {
            int t = atomicAdd(&cnt, 1);
            if (t < CAP) { ss[t] = p.z; si[t] = 2 * q + 1; }
        }
    }
    __syncthreads();

    int m = cnt;
    if (m > CAP) m = CAP;

    // bitonic sort over P = next pow2 >= m, pad with -inf sentinels
    int P = 2;
    while (P < m) P <<= 1;
    for (int i = lane; i < P; i += 64) {
        if (i >= m) { ss[i] = -INFINITY; si[i] = 0x7FFFFFFF; }
    }
    __syncthreads();

    for (int size = 2; size <= P; size <<= 1) {
        for (int stride = size >> 1; stride > 0; stride >>= 1) {
            for (int t = lane; t < P / 2; t += 64) {
                int lo = 2 * stride * (t / stride) + (t % stride);
                int hi = lo + stride;
                bool desc = ((lo & size) == 0);
                float slo = ss[lo], shi = ss[hi];
                int   ilo = si[lo], ihi = si[hi];
                bool loBetter = (slo > shi) || (slo == shi && ilo < ihi);
                bool doSwap = desc ? !loBetter : loBetter;
                if (doSwap) { ss[lo] = shi; ss[hi] = slo; si[lo] = ihi; si[hi] = ilo; }
            }
            __syncthreads();
        }
    }

    // load this lane's 4 candidates (sorted ranks lane, lane+64, ...) into regs
    float cx1[4], cy1[4], cx2[4], cy2[4], car[4];
    int   cidx[4];
    bool  cval[4];
#pragma unroll
    for (int s = 0; s < 4; s++) {
        int j = s * 64 + lane;
        cval[s] = (j < m);
        cidx[s] = 0;
        cx1[s] = 0.f; cy1[s] = 0.f; cx2[s] = 0.f; cy2[s] = 0.f; car[s] = 0.f;
        if (cval[s]) {
            int n = si[j];
            cidx[s] = n;
            float4 b = nmsBox[n];
            cx1[s] = b.x; cy1[s] = b.y; cx2[s] = b.z; cy2[s] = b.w;
            car[s] = nmsArea[n];
        }
    }

    // greedy: supp = 4-bit register mask per lane; no LDS, no barriers
    int sp = 0;
    for (int k = 0; k < m; k++) {
        const int owner = k & 63, slot = k >> 6;
        int pk = __shfl(sp, owner);
        if ((pk >> slot) & 1) continue;                 // pivot suppressed

        float vx1 = (slot == 0) ? cx1[0] : (slot == 1) ? cx1[1] : (slot == 2) ? cx1[2] : cx1[3];
        float vy1 = (slot == 0) ? cy1[0] : (slot == 1) ? cy1[1] : (slot == 2) ? cy1[2] : cy1[3];
        float vx2 = (slot == 0) ? cx2[0] : (slot == 1) ? cx2[1] : (slot == 2) ? cx2[2] : cx2[3];
        float vy2 = (slot == 0) ? cy2[0] : (slot == 1) ? cy2[1] : (slot == 2) ? cy2[2] : cy2[3];
        float var = (slot == 0) ? car[0] : (slot == 1) ? car[1] : (slot == 2) ? car[2] : car[3];
        float px1 = __shfl(vx1, owner);
        float py1 = __shfl(vy1, owner);
        float px2 = __shfl(vx2, owner);
        float py2 = __shfl(vy2, owner);
        float pa  = __shfl(var, owner);

#pragma unroll
        for (int s = 0; s < 4; s++) {
            if (s * 64 + 63 <= k) continue;             // whole slot <= k (uniform)
            int j = s * 64 + lane;
            if (j > k && j < m) {
                float xx1 = fmaxf(px1, cx1[s]);
                float yy1 = fmaxf(py1, cy1[s]);
                float xx2 = fminf(px2, cx2[s]);
                float yy2 = fminf(py2, cy2[s]);
                float inter = fmaxf(1e-10f, xx2 - xx1) * fmaxf(1e-10f, yy2 - yy1);
                float iou = inter / ((pa + car[s] - inter) + 1e-14f);
                if (iou > 0.5f) sp |= (1 << s);
            }
        }
    }

    // scatter keep bits
#pragma unroll
    for (int s = 0; s < 4; s++) {
        if (cval[s] && !((sp >> s) & 1)) keepOut[cidx[s]] = 1.0f;
    }
}

// ---------------------------------------------------------------------------
extern "C" void kernel_launch(void* const* d_in, const int* in_sizes, int n_in,
                              void* d_out, int out_size, void* d_ws, size_t ws_size,
                              hipStream_t stream) {
    const float* cls_feat = (const float*)d_in[0];
    const float* reg_feat = (const float*)d_in[1];
    const float* w_obj    = (const float*)d_in[2];
    const float* b_obj    = (const float*)d_in[3];
    const float* w_cls    = (const float*)d_in[4];
    const float* b_cls    = (const float*)d_in[5];
    const float* w_reg    = (const float*)d_in[6];
    const float* b_reg    = (const float*)d_in[7];

    float* out = (float*)d_out;
    float* ws  = (float*)d_ws;

    // workspace layout (floats)
    float*  clsRaw    = ws;                       // 640000
    float*  roRaw     = ws + 640000;              // 40000
    float4* nmsBox    = (float4*)(ws + 680000);   // 32000 floats (16B-aligned offset)
    float*  nmsArea   = ws + 712000;              // 8000
    float2* sl        = (float2*)(ws + 720000);   // 16000 floats (16B-aligned)
    // total 736000 floats = 2.944 MB

    k_gemm<<<dim3(25, 27), 256, 0, stream>>>(cls_feat, reg_feat,
                                             w_obj, b_obj, w_cls, b_cls, w_reg, b_reg,
                                             clsRaw, roRaw);
    k_box<<<NBOX / 4, 256, 0, stream>>>(clsRaw, roRaw, out, nmsBox, nmsArea, sl);
    k_nms<<<NCLS, 64, 0, stream>>>(sl, nmsBox, nmsArea, out + 48000);
}

// Round 7
// 185.842 us; speedup vs baseline: 1.1780x; 1.1780x over previous
//
#include <hip/hip_runtime.h>
#include <math.h>

#define FMPX 40
#define NPOS 1600          // 40*40
#define NCLS 80
#define NBOX 8000
#define KDIM 512
#define CAP  256           // per-class candidate capacity (mean ~100/class, +15 sigma)

// anchor (w,h) pairs
__constant__ float c_aw[5] = {17.f, 55.f, 92.f, 202.f, 289.f};
__constant__ float c_ah[5] = {25.f, 75.f, 206.f, 21.f, 311.f};

__device__ __forceinline__ float sigf(float x) { return 1.0f / (1.0f + expf(-x)); }

// ---------------------------------------------------------------------------
// K1: the three 1x1-conv GEMMs.
// History: R3 A+W LDS = LDS-bound 50us. R4/R6 W via s_load = 77/81us (scalar
// K$ ~16KB < 32KB W set -> per-step dependent L2 misses; scalar pipe DEAD for
// per-step operands). R5 W LDS-b128 + A global = 43us, LDS-bound: one b128
// (12cyc) feeds only M/16 FMA instr (8cyc at M=64).
// R7: M=128 per wave (2 positions/lane) flips the ratio (16cyc FMA per 12cyc
// LDS -> VALU-bound, floor ~42.5K cyc/CU ~ 18us) + single-wave 64-thr blocks
// (1391 blocks: finest balance, no barriers). W tile 4 rows = 8KB LDS,
// broadcast ds_read_b128; A global coalesced, register double-buffered.
// grid = (13 M-tiles of 128 pos, 107 N-tiles of 4 outs):
//   nTile 0..99: cls (cls_feat); 100..106: the 25 obj+reg outs (reg_feat).
// Per-output FMA order strictly sequential ascending k, operand form a*w —
// bitwise-identical to R1-R6 (absmax stable at 2.0 across all rounds).
// ---------------------------------------------------------------------------
__global__ __launch_bounds__(64) void k_gemm(
    const float* __restrict__ cls_feat, const float* __restrict__ reg_feat,
    const float* __restrict__ w_obj, const float* __restrict__ b_obj,
    const float* __restrict__ w_cls, const float* __restrict__ b_cls,
    const float* __restrict__ w_reg, const float* __restrict__ b_reg,
    float* __restrict__ clsRaw,   // [1600][400]
    float* __restrict__ roRaw)    // [1600][25]: 0..4 obj, 5..24 reg
{
    __shared__ float Ws[4 * KDIM];         // 8 KB
    const int mTile = blockIdx.x;          // 0..12
    const int nTile = blockIdx.y;          // 0..106
    const int hw0   = mTile * 128;
    const bool isCls = (nTile < 100);
    const float* feat = isCls ? cls_feat : reg_feat;
    const int lane = threadIdx.x;
    const int oBase = isCls ? nTile * 4 : (nTile - 100) * 4;

    // ---- stage W tile [4][512] (8 float4 per lane, coalesced) ----
    for (int i = lane * 4; i < 4 * KDIM; i += 64 * 4) {
        int r = i >> 9, k = i & 511;
        const float* src;
        bool valid = true;
        if (isCls) {
            src = w_cls + (oBase + r) * KDIM + k;
        } else {
            int o = oBase + r;
            if (o < 5)       src = w_obj + o * KDIM + k;
            else if (o < 25) src = w_reg + (o - 5) * KDIM + k;
            else           { src = w_obj; valid = false; }
        }
        float4 v = valid ? *(const float4*)src : make_float4(0.f, 0.f, 0.f, 0.f);
        *(float4*)&Ws[i] = v;
    }

    float bias[4];
    bool ok[4];
#pragma unroll
    for (int j = 0; j < 4; j++) {
        int o = oBase + j;
        if (isCls)      { bias[j] = b_cls[o];     ok[j] = true; }
        else if (o < 5) { bias[j] = b_obj[o];     ok[j] = true; }
        else if (o < 25){ bias[j] = b_reg[o - 5]; ok[j] = true; }
        else            { bias[j] = 0.0f;         ok[j] = false; }
    }

    // two positions per lane: pos0 = hw0+lane (always < 1600), pos1 = +64
    // (invalid only in the last partial M-tile -> clamp pointer, mask store)
    const bool ok1 = (hw0 + 64 + lane) < NPOS;
    const float* apa = feat + hw0 + lane;
    const float* apb = feat + (ok1 ? hw0 + 64 + lane : hw0 + lane);

    // initial A prefetch (k = 0..15), register double buffer, both positions
    float A0a[8], A0b[8], A1a[8], A1b[8];
#pragma unroll
    for (int t = 0; t < 8; t++) { A0a[t] = apa[t * NPOS];       A0b[t] = apb[t * NPOS]; }
#pragma unroll
    for (int t = 0; t < 8; t++) { A1a[t] = apa[(8 + t) * NPOS]; A1b[t] = apb[(8 + t) * NPOS]; }

    __syncthreads();   // single-wave block: effectively just a waitcnt

    float acc[4], acd[4];
#pragma unroll
    for (int j = 0; j < 4; j++) { acc[j] = 0.f; acd[j] = 0.f; }

    for (int kk = 0; kk < KDIM - 16; kk += 16) {
#pragma unroll
        for (int j = 0; j < 4; j++) {
            const float* wp = &Ws[j * KDIM + kk];      // LDS b128 x2, broadcast
#pragma unroll
            for (int t = 0; t < 8; t++) {
                acc[j] += A0a[t] * wp[t];
                acd[j] += A0b[t] * wp[t];
            }
        }
#pragma unroll
        for (int t = 0; t < 8; t++) { A0a[t] = apa[(kk + 16 + t) * NPOS]; A0b[t] = apb[(kk + 16 + t) * NPOS]; }
#pragma unroll
        for (int j = 0; j < 4; j++) {
            const float* wp = &Ws[j * KDIM + kk + 8];
#pragma unroll
            for (int t = 0; t < 8; t++) {
                acc[j] += A1a[t] * wp[t];
                acd[j] += A1b[t] * wp[t];
            }
        }
#pragma unroll
        for (int t = 0; t < 8; t++) { A1a[t] = apa[(kk + 24 + t) * NPOS]; A1b[t] = apb[(kk + 24 + t) * NPOS]; }
    }
    {   // tail: k = 496..511
        const int kk = KDIM - 16;
#pragma unroll
        for (int j = 0; j < 4; j++) {
            const float* wp = &Ws[j * KDIM + kk];
#pragma unroll
            for (int t = 0; t < 8; t++) {
                acc[j] += A0a[t] * wp[t];
                acd[j] += A0b[t] * wp[t];
            }
        }
#pragma unroll
        for (int j = 0; j < 4; j++) {
            const float* wp = &Ws[j * KDIM + kk + 8];
#pragma unroll
            for (int t = 0; t < 8; t++) {
                acc[j] += A1a[t] * wp[t];
                acd[j] += A1b[t] * wp[t];
            }
        }
    }

    const int hw  = hw0 + lane;
    const int hw2 = hw + 64;
    if (isCls) {
        float4 r0 = make_float4(acc[0] + bias[0], acc[1] + bias[1],
                                acc[2] + bias[2], acc[3] + bias[3]);
        *(float4*)&clsRaw[hw * 400 + oBase] = r0;
        if (ok1) {
            float4 r1 = make_float4(acd[0] + bias[0], acd[1] + bias[1],
                                    acd[2] + bias[2], acd[3] + bias[3]);
            *(float4*)&clsRaw[hw2 * 400 + oBase] = r1;
        }
    } else {
#pragma unroll
        for (int j = 0; j < 4; j++) {
            int o = oBase + j;
            if (ok[j]) {
                roRaw[hw * 25 + o] = acc[j] + bias[j];
                if (ok1) roRaw[hw2 * 25 + o] = acd[j] + bias[j];
            }
        }
    }
}

// ---------------------------------------------------------------------------
// K2: per-box scores, argmax label, decode, outputs. float4 class loads:
// lanes 0..19 cover 4 classes each (in-lane first-max, cross-lane lowest-
// index tiebreak == jnp.argmax first-max semantics).
// 2000 blocks x 256 thr; each of the 4 waves handles one box.
// ---------------------------------------------------------------------------
__global__ __launch_bounds__(256) void k_box(
    const float* __restrict__ clsRaw, const float* __restrict__ roRaw,
    float* __restrict__ out,          // d_out: [32000 bboxes][8000 score][8000 labels][8000 keep]
    float4* __restrict__ nmsBox, float* __restrict__ nmsArea,
    float2* __restrict__ sl)          // packed (score,label) for k_nms scan
{
    const int n = blockIdx.x * 4 + (threadIdx.x >> 6);   // box index 0..7999
    const int lane = threadIdx.x & 63;
    const int hw = n / 5, a = n % 5;

    const float sobj = sigf(roRaw[hw * 25 + a]);
    const float* cbase = clsRaw + hw * 400 + a * 80;

    const int l4 = (lane < 20) ? lane : 19;     // clamp for safe address
    float4 cs = *(const float4*)(cbase + l4 * 4);

    // in-lane first-max over classes l4*4 .. l4*4+3 (strict > keeps first)
    float s0 = sqrtf(sobj * sigf(cs.x));
    float s1 = sqrtf(sobj * sigf(cs.y));
    float s2 = sqrtf(sobj * sigf(cs.z));
    float s3 = sqrtf(sobj * sigf(cs.w));
    float v = s0; int bi = l4 * 4;
    if (s1 > v) { v = s1; bi = l4 * 4 + 1; }
    if (s2 > v) { v = s2; bi = l4 * 4 + 2; }
    if (s3 > v) { v = s3; bi = l4 * 4 + 3; }
    if (lane >= 20) { v = -1.0f; bi = 0x7FFFFFFF; }  // scores are always > 0

    // cross-lane: max score, ties -> lowest class
#pragma unroll
    for (int off = 32; off >= 1; off >>= 1) {
        float ov = __shfl_xor(v, off);
        int   oi = __shfl_xor(bi, off);
        if (ov > v || (ov == v && oi < bi)) { v = ov; bi = oi; }
    }

    if (lane == 0) {
        const float* rp = roRaw + hw * 25 + 5 + a * 4;
        float r0 = rp[0], r1 = rp[1], r2 = rp[2], r3 = rp[3];
        float gx = (float)(hw % FMPX), gy = (float)(hw / FMPX);
        float cx = (sigf(r0) + gx) * 32.0f;
        float cy = (sigf(r1) + gy) * 32.0f;
        float wv = expf(r2) * c_aw[a];
        float hv = expf(r3) * c_ah[a];
        float x1 = cx - wv * 0.5f, y1 = cy - hv * 0.5f;
        float x2 = cx + wv * 0.5f, y2 = cy + hv * 0.5f;

        out[n * 4 + 0] = x1; out[n * 4 + 1] = y1;
        out[n * 4 + 2] = x2; out[n * 4 + 3] = y2;
        out[32000 + n] = v;
        out[40000 + n] = (float)bi;
        out[48000 + n] = 0.0f;            // keep init (k_nms sets 1s later)
        sl[n] = make_float2(v, (float)bi);

        // b2: reinterpret x1y1x2y2 as cxcywh (faithful to the reference nms())
        float nx1 = x1 - x2 * 0.5f, ny1 = y1 - y2 * 0.5f;
        float nx2 = x1 + x2 * 0.5f, ny2 = y1 + y2 * 0.5f;
        nmsBox[n]  = make_float4(nx1, ny1, nx2, ny2);
        nmsArea[n] = (nx2 - nx1) * (ny2 - ny1);
    }
}

// ---------------------------------------------------------------------------
// K3: per-class greedy NMS — ONE WAVE per class, register-resident greedy.
// Candidates in registers (4 slots/lane, CAP=256), supp = 4-bit register
// mask/lane, pivot box + supp bit broadcast via slot-select + __shfl. LDS
// only for compaction + bitonic sort (deterministic (score desc, idx asc)
// == stable argsort(-score) per class). No barriers/LDS in the m-loop.
// ---------------------------------------------------------------------------
__global__ __launch_bounds__(64) void k_nms(
    const float2* __restrict__ sl,
    const float4* __restrict__ nmsBox, const float* __restrict__ nmsArea,
    float* __restrict__ keepOut)
{
    const int c = blockIdx.x;
    const int lane = threadIdx.x;

    __shared__ float ss[CAP];
    __shared__ int   si[CAP];
    __shared__ int   cnt;

    if (lane == 0) cnt = 0;
    __syncthreads();

    // scan all boxes, 2 per float4 load, compact matches into LDS
    const float4* sl4 = (const float4*)sl;
    for (int q = lane; q < NBOX / 2; q += 64) {
        float4 p = sl4[q];
        if (p.x >= 0.3f && (int)p.y == c) {
            int t = atomicAdd(&cnt, 1);
            if (t < CAP) { ss[t] = p.x; si[t] = 2 * q; }
        }
        if (p.z >= 0.3f && (int)p.w == c) {
            int t = atomicAdd(&cnt, 1);
            if (t < CAP) { ss[t] = p.z; si[t] = 2 * q + 1; }
        }
    }
    __syncthreads();

    int m = cnt;
    if (m > CAP) m = CAP;

    // bitonic sort over P = next pow2 >= m, pad with -inf sentinels
    int P = 2;
    while (P < m) P <<= 1;
    for (int i = lane; i < P; i += 64) {
        if (i >= m) { ss[i] = -INFINITY; si[i] = 0x7FFFFFFF; }
    }
    __syncthreads();

    for (int size = 2; size <= P; size <<= 1) {
        for (int stride = size >> 1; stride > 0; stride >>= 1) {
            for (int t = lane; t < P / 2; t += 64) {
                int lo = 2 * stride * (t / stride) + (t % stride);
                int hi = lo + stride;
                bool desc = ((lo & size) == 0);
                float slo = ss[lo], shi = ss[hi];
                int   ilo = si[lo], ihi = si[hi];
                bool loBetter = (slo > shi) || (slo == shi && ilo < ihi);
                bool doSwap = desc ? !loBetter : loBetter;
                if (doSwap) { ss[lo] = shi; ss[hi] = slo; si[lo] = ihi; si[hi] = ilo; }
            }
            __syncthreads();
        }
    }

    // load this lane's 4 candidates (sorted ranks lane, lane+64, ...) into regs
    float cx1[4], cy1[4], cx2[4], cy2[4], car[4];
    int   cidx[4];
    bool  cval[4];
#pragma unroll
    for (int s = 0; s < 4; s++) {
        int j = s * 64 + lane;
        cval[s] = (j < m);
        cidx[s] = 0;
        cx1[s] = 0.f; cy1[s] = 0.f; cx2[s] = 0.f; cy2[s] = 0.f; car[s] = 0.f;
        if (cval[s]) {
            int n = si[j];
            cidx[s] = n;
            float4 b = nmsBox[n];
            cx1[s] = b.x; cy1[s] = b.y; cx2[s] = b.z; cy2[s] = b.w;
            car[s] = nmsArea[n];
        }
    }

    // greedy: supp = 4-bit register mask per lane; no LDS, no barriers
    int sp = 0;
    for (int k = 0; k < m; k++) {
        const int owner = k & 63, slot = k >> 6;
        int pk = __shfl(sp, owner);
        if ((pk >> slot) & 1) continue;                 // pivot suppressed

        float vx1 = (slot == 0) ? cx1[0] : (slot == 1) ? cx1[1] : (slot == 2) ? cx1[2] : cx1[3];
        float vy1 = (slot == 0) ? cy1[0] : (slot == 1) ? cy1[1] : (slot == 2) ? cy1[2] : cy1[3];
        float vx2 = (slot == 0) ? cx2[0] : (slot == 1) ? cx2[1] : (slot == 2) ? cx2[2] : cx2[3];
        float vy2 = (slot == 0) ? cy2[0] : (slot == 1) ? cy2[1] : (slot == 2) ? cy2[2] : cy2[3];
        float var = (slot == 0) ? car[0] : (slot == 1) ? car[1] : (slot == 2) ? car[2] : car[3];
        float px1 = __shfl(vx1, owner);
        float py1 = __shfl(vy1, owner);
        float px2 = __shfl(vx2, owner);
        float py2 = __shfl(vy2, owner);
        float pa  = __shfl(var, owner);

#pragma unroll
        for (int s = 0; s < 4; s++) {
            if (s * 64 + 63 <= k) continue;             // whole slot <= k (uniform)
            int j = s * 64 + lane;
            if (j > k && j < m) {
                float xx1 = fmaxf(px1, cx1[s]);
                float yy1 = fmaxf(py1, cy1[s]);
                float xx2 = fminf(px2, cx2[s]);
                float yy2 = fminf(py2, cy2[s]);
                float inter = fmaxf(1e-10f, xx2 - xx1) * fmaxf(1e-10f, yy2 - yy1);
                float iou = inter / ((pa + car[s] - inter) + 1e-14f);
                if (iou > 0.5f) sp |= (1 << s);
            }
        }
    }

    // scatter keep bits
#pragma unroll
    for (int s = 0; s < 4; s++) {
        if (cval[s] && !((sp >> s) & 1)) keepOut[cidx[s]] = 1.0f;
    }
}

// ---------------------------------------------------------------------------
extern "C" void kernel_launch(void* const* d_in, const int* in_sizes, int n_in,
                              void* d_out, int out_size, void* d_ws, size_t ws_size,
                              hipStream_t stream) {
    const float* cls_feat = (const float*)d_in[0];
    const float* reg_feat = (const float*)d_in[1];
    const float* w_obj    = (const float*)d_in[2];
    const float* b_obj    = (const float*)d_in[3];
    const float* w_cls    = (const float*)d_in[4];
    const float* b_cls    = (const float*)d_in[5];
    const float* w_reg    = (const float*)d_in[6];
    const float* b_reg    = (const float*)d_in[7];

    float* out = (float*)d_out;
    float* ws  = (float*)d_ws;

    // workspace layout (floats)
    float*  clsRaw    = ws;                       // 640000
    float*  roRaw     = ws + 640000;              // 40000
    float4* nmsBox    = (float4*)(ws + 680000);   // 32000 floats (16B-aligned offset)
    float*  nmsArea   = ws + 712000;              // 8000
    float2* sl        = (float2*)(ws + 720000);   // 16000 floats (16B-aligned)
    // total 736000 floats = 2.944 MB

    k_gemm<<<dim3(13, 107), 64, 0, stream>>>(cls_feat, reg_feat,
                                             w_obj, b_obj, w_cls, b_cls, w_reg, b_reg,
                                             clsRaw, roRaw);
    k_box<<<NBOX / 4, 256, 0, stream>>>(clsRaw, roRaw, out, nmsBox, nmsArea, sl);
    k_nms<<<NCLS, 64, 0, stream>>>(sl, nmsBox, nmsArea, out + 48000);
}

// Round 8
// 171.700 us; speedup vs baseline: 1.2750x; 1.0824x over previous
//
#include <hip/hip_runtime.h>
#include <math.h>

#define FMPX 40
#define NPOS 1600          // 40*40
#define NCLS 80
#define NBOX 8000
#define KDIM 512
#define CAP  256           // per-class candidate capacity (mean ~100/class, +15 sigma)

// anchor (w,h) pairs
__constant__ float c_aw[5] = {17.f, 55.f, 92.f, 202.f, 289.f};
__constant__ float c_ah[5] = {25.f, 75.f, 206.f, 21.f, 311.f};

__device__ __forceinline__ float sigf(float x) { return 1.0f / (1.0f + expf(-x)); }
__device__ __forceinline__ float rlanef(float v, int lane) {
    return __uint_as_float(__builtin_amdgcn_readlane(__float_as_uint(v), lane));
}

// ---------------------------------------------------------------------------
// K1: the three 1x1-conv GEMMs. (unchanged from R7 — out of top-5 there)
// M=128 per wave (2 positions/lane): one W ds_read_b128 (12cyc) feeds 16cyc
// of FMA -> VALU-bound. Single-wave 64-thr blocks, W tile 4 rows = 8KB LDS,
// A global coalesced register double-buffer. Scalar pipe for per-step W is
// DEAD (R4/R6: scalar K$ ~16KB -> per-step L2 misses, 77/81us).
// Per-output FMA order strictly sequential ascending k — bitwise-identical
// to R1-R7 (absmax stable at 2.0).
// ---------------------------------------------------------------------------
__global__ __launch_bounds__(64) void k_gemm(
    const float* __restrict__ cls_feat, const float* __restrict__ reg_feat,
    const float* __restrict__ w_obj, const float* __restrict__ b_obj,
    const float* __restrict__ w_cls, const float* __restrict__ b_cls,
    const float* __restrict__ w_reg, const float* __restrict__ b_reg,
    float* __restrict__ clsRaw,   // [1600][400]
    float* __restrict__ roRaw)    // [1600][25]: 0..4 obj, 5..24 reg
{
    __shared__ float Ws[4 * KDIM];         // 8 KB
    const int mTile = blockIdx.x;          // 0..12
    const int nTile = blockIdx.y;          // 0..106
    const int hw0   = mTile * 128;
    const bool isCls = (nTile < 100);
    const float* feat = isCls ? cls_feat : reg_feat;
    const int lane = threadIdx.x;
    const int oBase = isCls ? nTile * 4 : (nTile - 100) * 4;

    // ---- stage W tile [4][512] (8 float4 per lane, coalesced) ----
    for (int i = lane * 4; i < 4 * KDIM; i += 64 * 4) {
        int r = i >> 9, k = i & 511;
        const float* src;
        bool valid = true;
        if (isCls) {
            src = w_cls + (oBase + r) * KDIM + k;
        } else {
            int o = oBase + r;
            if (o < 5)       src = w_obj + o * KDIM + k;
            else if (o < 25) src = w_reg + (o - 5) * KDIM + k;
            else           { src = w_obj; valid = false; }
        }
        float4 v = valid ? *(const float4*)src : make_float4(0.f, 0.f, 0.f, 0.f);
        *(float4*)&Ws[i] = v;
    }

    float bias[4];
    bool ok[4];
#pragma unroll
    for (int j = 0; j < 4; j++) {
        int o = oBase + j;
        if (isCls)      { bias[j] = b_cls[o];     ok[j] = true; }
        else if (o < 5) { bias[j] = b_obj[o];     ok[j] = true; }
        else if (o < 25){ bias[j] = b_reg[o - 5]; ok[j] = true; }
        else            { bias[j] = 0.0f;         ok[j] = false; }
    }

    const bool ok1 = (hw0 + 64 + lane) < NPOS;
    const float* apa = feat + hw0 + lane;
    const float* apb = feat + (ok1 ? hw0 + 64 + lane : hw0 + lane);

    float A0a[8], A0b[8], A1a[8], A1b[8];
#pragma unroll
    for (int t = 0; t < 8; t++) { A0a[t] = apa[t * NPOS];       A0b[t] = apb[t * NPOS]; }
#pragma unroll
    for (int t = 0; t < 8; t++) { A1a[t] = apa[(8 + t) * NPOS]; A1b[t] = apb[(8 + t) * NPOS]; }

    __syncthreads();

    float acc[4], acd[4];
#pragma unroll
    for (int j = 0; j < 4; j++) { acc[j] = 0.f; acd[j] = 0.f; }

    for (int kk = 0; kk < KDIM - 16; kk += 16) {
#pragma unroll
        for (int j = 0; j < 4; j++) {
            const float* wp = &Ws[j * KDIM + kk];
#pragma unroll
            for (int t = 0; t < 8; t++) {
                acc[j] += A0a[t] * wp[t];
                acd[j] += A0b[t] * wp[t];
            }
        }
#pragma unroll
        for (int t = 0; t < 8; t++) { A0a[t] = apa[(kk + 16 + t) * NPOS]; A0b[t] = apb[(kk + 16 + t) * NPOS]; }
#pragma unroll
        for (int j = 0; j < 4; j++) {
            const float* wp = &Ws[j * KDIM + kk + 8];
#pragma unroll
            for (int t = 0; t < 8; t++) {
                acc[j] += A1a[t] * wp[t];
                acd[j] += A1b[t] * wp[t];
            }
        }
#pragma unroll
        for (int t = 0; t < 8; t++) { A1a[t] = apa[(kk + 24 + t) * NPOS]; A1b[t] = apb[(kk + 24 + t) * NPOS]; }
    }
    {
        const int kk = KDIM - 16;
#pragma unroll
        for (int j = 0; j < 4; j++) {
            const float* wp = &Ws[j * KDIM + kk];
#pragma unroll
            for (int t = 0; t < 8; t++) {
                acc[j] += A0a[t] * wp[t];
                acd[j] += A0b[t] * wp[t];
            }
        }
#pragma unroll
        for (int j = 0; j < 4; j++) {
            const float* wp = &Ws[j * KDIM + kk + 8];
#pragma unroll
            for (int t = 0; t < 8; t++) {
                acc[j] += A1a[t] * wp[t];
                acd[j] += A1b[t] * wp[t];
            }
        }
    }

    const int hw  = hw0 + lane;
    const int hw2 = hw + 64;
    if (isCls) {
        float4 r0 = make_float4(acc[0] + bias[0], acc[1] + bias[1],
                                acc[2] + bias[2], acc[3] + bias[3]);
        *(float4*)&clsRaw[hw * 400 + oBase] = r0;
        if (ok1) {
            float4 r1 = make_float4(acd[0] + bias[0], acd[1] + bias[1],
                                    acd[2] + bias[2], acd[3] + bias[3]);
            *(float4*)&clsRaw[hw2 * 400 + oBase] = r1;
        }
    } else {
#pragma unroll
        for (int j = 0; j < 4; j++) {
            int o = oBase + j;
            if (ok[j]) {
                roRaw[hw * 25 + o] = acc[j] + bias[j];
                if (ok1) roRaw[hw2 * 25 + o] = acd[j] + bias[j];
            }
        }
    }
}

// ---------------------------------------------------------------------------
// K2: per-box scores, argmax label, decode, outputs. (unchanged from R7)
// ---------------------------------------------------------------------------
__global__ __launch_bounds__(256) void k_box(
    const float* __restrict__ clsRaw, const float* __restrict__ roRaw,
    float* __restrict__ out,          // d_out: [32000 bboxes][8000 score][8000 labels][8000 keep]
    float4* __restrict__ nmsBox, float* __restrict__ nmsArea,
    float2* __restrict__ sl)          // packed (score,label) for k_nms scan
{
    const int n = blockIdx.x * 4 + (threadIdx.x >> 6);   // box index 0..7999
    const int lane = threadIdx.x & 63;
    const int hw = n / 5, a = n % 5;

    const float sobj = sigf(roRaw[hw * 25 + a]);
    const float* cbase = clsRaw + hw * 400 + a * 80;

    const int l4 = (lane < 20) ? lane : 19;     // clamp for safe address
    float4 cs = *(const float4*)(cbase + l4 * 4);

    float s0 = sqrtf(sobj * sigf(cs.x));
    float s1 = sqrtf(sobj * sigf(cs.y));
    float s2 = sqrtf(sobj * sigf(cs.z));
    float s3 = sqrtf(sobj * sigf(cs.w));
    float v = s0; int bi = l4 * 4;
    if (s1 > v) { v = s1; bi = l4 * 4 + 1; }
    if (s2 > v) { v = s2; bi = l4 * 4 + 2; }
    if (s3 > v) { v = s3; bi = l4 * 4 + 3; }
    if (lane >= 20) { v = -1.0f; bi = 0x7FFFFFFF; }

#pragma unroll
    for (int off = 32; off >= 1; off >>= 1) {
        float ov = __shfl_xor(v, off);
        int   oi = __shfl_xor(bi, off);
        if (ov > v || (ov == v && oi < bi)) { v = ov; bi = oi; }
    }

    if (lane == 0) {
        const float* rp = roRaw + hw * 25 + 5 + a * 4;
        float r0 = rp[0], r1 = rp[1], r2 = rp[2], r3 = rp[3];
        float gx = (float)(hw % FMPX), gy = (float)(hw / FMPX);
        float cx = (sigf(r0) + gx) * 32.0f;
        float cy = (sigf(r1) + gy) * 32.0f;
        float wv = expf(r2) * c_aw[a];
        float hv = expf(r3) * c_ah[a];
        float x1 = cx - wv * 0.5f, y1 = cy - hv * 0.5f;
        float x2 = cx + wv * 0.5f, y2 = cy + hv * 0.5f;

        out[n * 4 + 0] = x1; out[n * 4 + 1] = y1;
        out[n * 4 + 2] = x2; out[n * 4 + 3] = y2;
        out[32000 + n] = v;
        out[40000 + n] = (float)bi;
        out[48000 + n] = 0.0f;            // keep init (k_nms sets 1s later)
        sl[n] = make_float2(v, (float)bi);

        // b2: reinterpret x1y1x2y2 as cxcywh (faithful to the reference nms())
        float nx1 = x1 - x2 * 0.5f, ny1 = y1 - y2 * 0.5f;
        float nx2 = x1 + x2 * 0.5f, ny2 = y1 + y2 * 0.5f;
        nmsBox[n]  = make_float4(nx1, ny1, nx2, ny2);
        nmsArea[n] = (nx2 - nx1) * (ny2 - ny1);
    }
}

// ---------------------------------------------------------------------------
// K3: per-class greedy NMS — one wave per class.
// R7 lesson (71us, VALUBusy 1%): (a) scan had 1 load in flight -> 62 serial
// HBM latencies; (b) m-loop used 7 ds_bpermute shfls + 20-deep cndmask
// slot-select per iteration. R8: (a) scan batches 8 independent float4 loads
// into registers before processing (8 latencies total); (b) m-loop chunked
// by pivot slot (slot = compile-time constant) + v_readlane broadcasts
// (owner = k&63 is SGPR-uniform) -> ~70cyc/iter chain.
// Sort unchanged: bitonic by (score desc, idx asc) == stable argsort(-score).
// ---------------------------------------------------------------------------
__global__ __launch_bounds__(64) void k_nms(
    const float2* __restrict__ sl,
    const float4* __restrict__ nmsBox, const float* __restrict__ nmsArea,
    float* __restrict__ keepOut)
{
    const int c = blockIdx.x;
    const int lane = threadIdx.x;

    __shared__ float ss[CAP];
    __shared__ int   si[CAP];
    __shared__ int   cnt;

    if (lane == 0) cnt = 0;
    __syncthreads();

    // ---- scan: ILP-8 batched loads, 2 candidates per float4 ----
    const float4* sl4 = (const float4*)sl;          // 4000 entries
    for (int base = 0; base < NBOX / 2; base += 512) {
        float4 buf[8];
#pragma unroll
        for (int b = 0; b < 8; b++) {
            int q = base + b * 64 + lane;
            buf[b] = (q < NBOX / 2) ? sl4[q] : make_float4(0.f, 0.f, 0.f, 0.f);
        }
#pragma unroll
        for (int b = 0; b < 8; b++) {
            int q = base + b * 64 + lane;
            if (q < NBOX / 2) {
                if (buf[b].x >= 0.3f && (int)buf[b].y == c) {
                    int t = atomicAdd(&cnt, 1);
                    if (t < CAP) { ss[t] = buf[b].x; si[t] = 2 * q; }
                }
                if (buf[b].z >= 0.3f && (int)buf[b].w == c) {
                    int t = atomicAdd(&cnt, 1);
                    if (t < CAP) { ss[t] = buf[b].z; si[t] = 2 * q + 1; }
                }
            }
        }
    }
    __syncthreads();

    int m = cnt;
    if (m > CAP) m = CAP;

    // ---- bitonic sort over P = next pow2 >= m ----
    int P = 2;
    while (P < m) P <<= 1;
    for (int i = lane; i < P; i += 64) {
        if (i >= m) { ss[i] = -INFINITY; si[i] = 0x7FFFFFFF; }
    }
    __syncthreads();

    for (int size = 2; size <= P; size <<= 1) {
        for (int stride = size >> 1; stride > 0; stride >>= 1) {
            for (int t = lane; t < P / 2; t += 64) {
                int lo = 2 * stride * (t / stride) + (t % stride);
                int hi = lo + stride;
                bool desc = ((lo & size) == 0);
                float slo = ss[lo], shi = ss[hi];
                int   ilo = si[lo], ihi = si[hi];
                bool loBetter = (slo > shi) || (slo == shi && ilo < ihi);
                bool doSwap = desc ? !loBetter : loBetter;
                if (doSwap) { ss[lo] = shi; ss[hi] = slo; si[lo] = ihi; si[hi] = ilo; }
            }
            __syncthreads();
        }
    }

    // ---- gather candidates into registers (4 slots/lane) ----
    float cx1[4], cy1[4], cx2[4], cy2[4], car[4];
    int   cidx[4];
    bool  cval[4];
#pragma unroll
    for (int s = 0; s < 4; s++) {
        int j = s * 64 + lane;
        cval[s] = (j < m);
        cidx[s] = 0;
        cx1[s] = 0.f; cy1[s] = 0.f; cx2[s] = 0.f; cy2[s] = 0.f; car[s] = 0.f;
        if (cval[s]) {
            int n = si[j];
            cidx[s] = n;
            float4 b = nmsBox[n];
            cx1[s] = b.x; cy1[s] = b.y; cx2[s] = b.z; cy2[s] = b.w;
            car[s] = nmsArea[n];
        }
    }

    // ---- greedy: chunked by pivot slot (compile-time), readlane broadcasts ----
    int sp = 0;
#pragma unroll
    for (int s0 = 0; s0 < 4; s0++) {
        const int kend = (m < (s0 + 1) * 64) ? m : (s0 + 1) * 64;
        for (int k = s0 * 64; k < kend; k++) {
            const int owner = k & 63;                       // SGPR-uniform
            int pk = __builtin_amdgcn_readlane(sp, owner);
            if ((pk >> s0) & 1) continue;                   // pivot suppressed

            float px1 = rlanef(cx1[s0], owner);
            float py1 = rlanef(cy1[s0], owner);
            float px2 = rlanef(cx2[s0], owner);
            float py2 = rlanef(cy2[s0], owner);
            float pa  = rlanef(car[s0], owner);

#pragma unroll
            for (int s = s0; s < 4; s++) {
                int j = s * 64 + lane;
                if (j > k && j < m) {
                    float xx1 = fmaxf(px1, cx1[s]);
                    float yy1 = fmaxf(py1, cy1[s]);
                    float xx2 = fminf(px2, cx2[s]);
                    float yy2 = fminf(py2, cy2[s]);
                    float inter = fmaxf(1e-10f, xx2 - xx1) * fmaxf(1e-10f, yy2 - yy1);
                    float iou = inter / ((pa + car[s] - inter) + 1e-14f);
                    if (iou > 0.5f) sp |= (1 << s);
                }
            }
        }
    }

    // ---- scatter keep bits ----
#pragma unroll
    for (int s = 0; s < 4; s++) {
        if (cval[s] && !((sp >> s) & 1)) keepOut[cidx[s]] = 1.0f;
    }
}

// ---------------------------------------------------------------------------
extern "C" void kernel_launch(void* const* d_in, const int* in_sizes, int n_in,
                              void* d_out, int out_size, void* d_ws, size_t ws_size,
                              hipStream_t stream) {
    const float* cls_feat = (const float*)d_in[0];
    const float* reg_feat = (const float*)d_in[1];
    const float* w_obj    = (const float*)d_in[2];
    const float* b_obj    = (const float*)d_in[3];
    const float* w_cls    = (const float*)d_in[4];
    const float* b_cls    = (const float*)d_in[5];
    const float* w_reg    = (const float*)d_in[6];
    const float* b_reg    = (const float*)d_in[7];

    float* out = (float*)d_out;
    float* ws  = (float*)d_ws;

    // workspace layout (floats)
    float*  clsRaw    = ws;                       // 640000
    float*  roRaw     = ws + 640000;              // 40000
    float4* nmsBox    = (float4*)(ws + 680000);   // 32000 floats (16B-aligned offset)
    float*  nmsArea   = ws + 712000;              // 8000
    float2* sl        = (float2*)(ws + 720000);   // 16000 floats (16B-aligned)
    // total 736000 floats = 2.944 MB

    k_gemm<<<dim3(13, 107), 64, 0, stream>>>(cls_feat, reg_feat,
                                             w_obj, b_obj, w_cls, b_cls, w_reg, b_reg,
                                             clsRaw, roRaw);
    k_box<<<NBOX / 4, 256, 0, stream>>>(clsRaw, roRaw, out, nmsBox, nmsArea, sl);
    k_nms<<<NCLS, 64, 0, stream>>>(sl, nmsBox, nmsArea, out + 48000);
}